// Round 10
// baseline (174.834 us; speedup 1.0000x reference)
//
#include <hip/hip_runtime.h>

// VQ-VAE vector quantizer, MI355X — MFMA candidate-filter + exact fp32 recheck.
// z_e: [32,64,32,32] f32, codebook: [1024,64] f32.
// d_out = q_out(2097152) | loss(1) | perplexity(1) | encodings(33554432), all f32.
//
// Pipeline:
//   1. vq_prep_kernel    : codebook->bf16, squared norms (exact chain), hist zero
//   2. vq_argmin_kernel  : MFMA approx distances (2 passes) -> candidate flags ->
//                          exact fp32 recheck + q_out + loss + hist + idx
//   3. vq_encfill_kernel : zero the 134 MB one-hot buffer (plain dwordx4 stream,
//                          L2 write-combined) + per-row 1.0 scatter
//   4. vq_finalize_kernel: loss mean + perplexity
//
// r9 lesson: fusing NONTEMPORAL 8B fills into the MFMA loop shares the vmcnt
// queue — every b-frag load wait drains an HBM-latency nt store => whole
// kernel at ~1 TB/s, all pipes idle. Decouple: compute kernel does compute,
// fill kernel streams plain x4 stores at natural write BW.
//
// Correctness: selection is ALWAYS by exact fp32 d = (zsq + ensq) - 2*dot with
// sequential fmaf chains (c ascending) and lower-index tie-break — same bits
// as rounds 1-7 (absmax 0). MFMA only prunes (margin covers bf16 error bound).
//
// ws layout (4-byte units):
//   [0,1024)       hist (int)
//   [1024,2048)    ensq (float)
//   [2048,34816)   cb_bf16 (1024x64 ushort)
//   [34816,35328)  partials (float[512])
//   [35328,68096)  idx (int[32768])

#define NROWS 32768
#define KC    1024
#define DD    64
#define HW    1024
#define CHW   65536

typedef float f32x2 __attribute__((ext_vector_type(2)));
typedef float f32x4 __attribute__((ext_vector_type(4)));
typedef short bf16x8 __attribute__((ext_vector_type(8)));

__device__ __forceinline__ unsigned short f2bf(float f) {
  unsigned x = __float_as_uint(f);
  return (unsigned short)((x + 0x7fffu + ((x >> 16) & 1u)) >> 16);  // RNE
}

__global__ __launch_bounds__(256) void vq_prep_kernel(
    const float* __restrict__ cb, float* __restrict__ ensq,
    unsigned short* __restrict__ cbb, int* __restrict__ hist) {
  int k = blockIdx.x * 256 + threadIdx.x;   // 4 blocks x 256 = exactly KC
  hist[k] = 0;
  const float* row = cb + k * DD;
  float s = 0.f;
#pragma unroll
  for (int c = 0; c < DD; ++c) {
    float v = row[c];
    s = fmaf(v, v, s);                      // exact chain, c ascending
    cbb[k * DD + c] = f2bf(v);
  }
  ensq[k] = s;
}

__global__ __launch_bounds__(512) void vq_argmin_kernel(
    const float* __restrict__ z_e, const float* __restrict__ cb,
    const unsigned short* __restrict__ cbb, const float* __restrict__ ensq_g,
    float* __restrict__ qout, int* __restrict__ idx_out,
    int* __restrict__ hist, float* __restrict__ partials) {
  __shared__ float s_m[2][64];
  __shared__ float s_zsq[64];
  __shared__ unsigned long long s_key[64];
  __shared__ float s_loss[8];

  const int tid  = threadIdx.x;
  const int lane = tid & 63;
  const int wave = __builtin_amdgcn_readfirstlane(tid >> 6);
  const int rt   = wave & 3;    // row tile: rows [16rt, 16rt+16) of the block
  const int h    = wave >> 2;   // code half: codes [512h, 512h+512)
  const int cq   = lane >> 4;   // k-slice quarter 0..3
  const int cl   = lane & 15;   // col (code) / A-row index

  // prologue: exact zsq per row (sequential chain — same bits as r1-r7)
  if (wave == 0) {
    const int n0 = blockIdx.x * 64 + lane;
    const float* zp0 = z_e + (size_t)(n0 >> 10) * CHW + (n0 & (HW - 1));
    float s = 0.f;
#pragma unroll
    for (int c = 0; c < DD; ++c) {
      float v = zp0[(size_t)c << 10];
      s = fmaf(v, v, s);
    }
    s_zsq[lane] = s;
    s_key[lane] = ~0ull;
  }

  // A-frags: this wave's 16 z-rows as bf16. Lane l: row = cl, k = cq*8+i.
  const int n  = blockIdx.x * 64 + rt * 16 + cl;
  const int b  = n >> 10;
  const int hw = n & (HW - 1);
  const float* zp = z_e + (size_t)b * CHW + hw;
  bf16x8 a0, a1;
#pragma unroll
  for (int i = 0; i < 8; ++i) {
    a0[i] = (short)f2bf(zp[(size_t)(cq * 8 + i) << 10]);
    a1[i] = (short)f2bf(zp[(size_t)(32 + cq * 8 + i) << 10]);
  }

  const int kbase = h * 512;
  // lane's b-frag pointer for t=0 (code = kbase + t*16 + cl); +1024 shorts per t
  const unsigned short* pb = cbb + (size_t)(kbase + cl) * DD + cq * 8;

  float bestm[4];
#pragma unroll
  for (int r = 0; r < 4; ++r) bestm[r] = 3.402823466e38f;

  // ---- pass 1: approx row-min over this wave's 512 codes (prefetched) ----
  {
    bf16x8 b0 = *(const bf16x8*)(pb);
    bf16x8 b1 = *(const bf16x8*)(pb + 32);
    for (int t = 0; t < 32; ++t) {
      bf16x8 nb0 = b0, nb1 = b1;
      if (t < 31) {
        nb0 = *(const bf16x8*)(pb + (t + 1) * 1024);
        nb1 = *(const bf16x8*)(pb + (t + 1) * 1024 + 32);
      }
      f32x4 acc = {0.f, 0.f, 0.f, 0.f};
      acc = __builtin_amdgcn_mfma_f32_16x16x32_bf16(a0, b0, acc, 0, 0, 0);
      acc = __builtin_amdgcn_mfma_f32_16x16x32_bf16(a1, b1, acc, 0, 0, 0);
#pragma unroll
      for (int r = 0; r < 4; ++r) bestm[r] = fminf(bestm[r], -2.0f * acc[r]);
      b0 = nb0; b1 = nb1;
    }
  }
  // reduce over the 16 cols (lane bits 0..3)
#pragma unroll
  for (int r = 0; r < 4; ++r) {
#pragma unroll
    for (int off = 1; off < 16; off <<= 1)
      bestm[r] = fminf(bestm[r], __shfl_xor(bestm[r], off, 64));
  }
  if (cl == 0) {
#pragma unroll
    for (int r = 0; r < 4; ++r) s_m[h][rt * 16 + cq * 4 + r] = bestm[r];
  }
  __syncthreads();

  // thresholds: global approx min + rigorous margin
  float th[4];
#pragma unroll
  for (int r = 0; r < 4; ++r) {
    const int lr = rt * 16 + cq * 4 + r;
    float mh = fminf(s_m[0][lr], s_m[1][lr]);
    th[r] = mh + 2.5e-4f * sqrtf(s_zsq[lr]) + 2.0e-4f;
  }

  // ---- pass 2: recompute (deterministic), flag, exact-check candidates ----
  {
    bf16x8 b0 = *(const bf16x8*)(pb);
    bf16x8 b1 = *(const bf16x8*)(pb + 32);
    for (int t = 0; t < 32; ++t) {
      bf16x8 nb0 = b0, nb1 = b1;
      if (t < 31) {
        nb0 = *(const bf16x8*)(pb + (t + 1) * 1024);
        nb1 = *(const bf16x8*)(pb + (t + 1) * 1024 + 32);
      }
      const int code = kbase + t * 16 + cl;
      f32x4 acc = {0.f, 0.f, 0.f, 0.f};
      acc = __builtin_amdgcn_mfma_f32_16x16x32_bf16(a0, b0, acc, 0, 0, 0);
      acc = __builtin_amdgcn_mfma_f32_16x16x32_bf16(a1, b1, acc, 0, 0, 0);
#pragma unroll
      for (int r = 0; r < 4; ++r) {
        const bool fl = (-2.0f * acc[r] <= th[r]);
        if (__any(fl)) {
          if (fl) {
            const int lr = rt * 16 + cq * 4 + r;
            const int n2 = blockIdx.x * 64 + lr;
            const float* zp2 = z_e + (size_t)(n2 >> 10) * CHW + (n2 & (HW - 1));
            const float* ce  = cb + (size_t)code * DD;
            float dot = 0.f;
#pragma unroll 8
            for (int c = 0; c < DD; ++c)
              dot = fmaf(zp2[(size_t)c << 10], ce[c], dot);   // exact chain
            float d = (s_zsq[lr] + ensq_g[code]) - 2.0f * dot; // exact d-grid
            unsigned long long key =
                ((unsigned long long)__float_as_uint(d) << 32) | (unsigned)code;
            atomicMin(&s_key[lr], key);  // min d, then min index (numpy tie-break)
          }
        }
      }
      b0 = nb0; b1 = nb1;
    }
  }
  __syncthreads();

  // winner per row (row = lane): hist + idx store
  const int bif = (int)(unsigned)(s_key[lane] & 0xffffffffull);
  if (wave == 0) {
    atomicAdd(&hist[bif], 1);
    idx_out[blockIdx.x * 64 + lane] = bif;
  }

  // fused epilogue: q_out write + loss partial (8 waves x 8 channels, row=lane)
  const int n3  = blockIdx.x * 64 + lane;
  const int b3  = n3 >> 10;
  const int hw3 = n3 & (HW - 1);
  const float* zp3   = z_e + (size_t)b3 * CHW + hw3;
  const float* cbrow = cb + (size_t)bif * DD;
  float* qp = qout + (size_t)b3 * CHW + hw3;
  float lacc = 0.f;
#pragma unroll
  for (int j = 0; j < 8; ++j) {
    int c = wave * 8 + j;
    float v    = cbrow[c];
    float zc   = zp3[(size_t)c << 10];
    float diff = v - zc;               // matches ref (quantized - ze)
    qp[(size_t)c << 10] = zc + diff;   // matches ref ze + (quantized - ze)
    lacc = fmaf(diff, diff, lacc);
  }
#pragma unroll
  for (int off = 32; off > 0; off >>= 1) lacc += __shfl_down(lacc, off, 64);
  if (lane == 0) s_loss[wave] = lacc;
  __syncthreads();
  if (tid == 0) {
    float t = 0.f;
#pragma unroll
    for (int w2 = 0; w2 < 8; ++w2) t += s_loss[w2];
    partials[blockIdx.x] = t;
  }
}

// Zero the one-hot buffer + scatter 1.0s. 16 rows/block, 256 threads, plain
// stores (L2 write-combining; nt was the r9 killer). enc base = d_out +
// 2097154 floats == 8 mod 16 B, so each 4 KB row is head f32x2 + 255 x f32x4
// + tail f32x2. Same block zeros and scatters its rows; __syncthreads (which
// drains vmcnt) orders the scatter after the zeros.
__global__ __launch_bounds__(256) void vq_encfill_kernel(
    const int* __restrict__ idx, float* __restrict__ enc) {
  const int tid = threadIdx.x;
  const int r   = tid >> 4;        // row 0..15
  const int m   = tid & 15;        // team member 0..15
  float* rowp = enc + (size_t)(blockIdx.x * 16 + r) * KC;
  const f32x2 z2 = {0.f, 0.f};
  const f32x4 z4 = {0.f, 0.f, 0.f, 0.f};
  if (m == 0) *(f32x2*)rowp = z2;
  f32x4* chunks = (f32x4*)(rowp + 2);   // 16B-aligned, 255 chunks
#pragma unroll
  for (int j = 0; j < 15; ++j) chunks[m + 16 * j] = z4;
  if (m < 15) chunks[m + 240] = z4;
  else        *(f32x2*)(rowp + 1022) = z2;
  __syncthreads();
  if (tid < 16) {
    const int n = blockIdx.x * 16 + tid;
    enc[(size_t)n * KC + idx[n]] = 1.0f;
  }
}

__global__ __launch_bounds__(1024) void vq_finalize_kernel(
    const int* __restrict__ hist, const float* __restrict__ partials,
    float* __restrict__ out_loss, float* __restrict__ out_ppl) {
  __shared__ float red[1024];
  const int t = threadIdx.x;

  float p   = (float)hist[t] * (1.0f / 32768.0f);
  float ent = p * logf(p + 1e-10f);
  red[t] = ent;
  __syncthreads();
  for (int s = 512; s > 0; s >>= 1) {
    if (t < s) red[t] += red[t + s];
    __syncthreads();
  }
  float entropy = red[0];
  __syncthreads();

  red[t] = (t < 512) ? partials[t] : 0.f;
  __syncthreads();
  for (int s = 512; s > 0; s >>= 1) {
    if (t < s) red[t] += red[t + s];
    __syncthreads();
  }
  if (t == 0) {
    *out_loss = 0.25f * (red[0] * (1.0f / 2097152.0f));
    *out_ppl  = expf(-entropy);
  }
}

extern "C" void kernel_launch(void* const* d_in, const int* in_sizes, int n_in,
                              void* d_out, int out_size, void* d_ws, size_t ws_size,
                              hipStream_t stream) {
  const float* z_e = (const float*)d_in[0];
  const float* cb  = (const float*)d_in[1];

  float* out  = (float*)d_out;
  float* qout = out;                       // 2097152
  float* loss = out + 2097152;
  float* ppl  = out + 2097153;
  float* enc  = out + 2097154;             // 33554432 floats

  int*            hist     = (int*)d_ws;
  float*          ensq     = (float*)d_ws + 1024;
  unsigned short* cbb      = (unsigned short*)((float*)d_ws + 2048);
  float*          partials = (float*)d_ws + 34816;
  int*            idx      = (int*)d_ws + 35328;

  vq_prep_kernel<<<4, 256, 0, stream>>>(cb, ensq, cbb, hist);
  vq_argmin_kernel<<<512, 512, 0, stream>>>(z_e, cb, cbb, ensq, qout, idx, hist, partials);
  vq_encfill_kernel<<<NROWS / 16, 256, 0, stream>>>(idx, enc);
  vq_finalize_kernel<<<1, 1024, 0, stream>>>(hist, partials, loss, ppl);
}

// Round 11
// 131.102 us; speedup vs baseline: 1.3336x; 1.3336x over previous
//
#include <hip/hip_runtime.h>

// VQ-VAE vector quantizer, MI355X — MFMA filter + queued exact fp32 recheck,
// with the 134 MB one-hot zero-fill overlapped as independent blocks.
// z_e: [32,64,32,32] f32, codebook: [1024,64] f32.
// d_out = q_out(2097152) | loss(1) | perplexity(1) | encodings(33554432), all f32.
//
// r10 lesson: the 150 us argmin was FRONTEND-bound — 32x-unrolled pass-2 with
// inline divergent rechecks = ~150 KB of code vs 32 KB I$; all pipes idle and
// store-removal changed nothing. Fix: unroll-1 loops, queue candidates to LDS,
// compact recheck phase, and spend the idle machine on the enc zero-fill.
//
// Correctness: selection is ALWAYS exact fp32 d = (zsq + ensq) - 2*dot with
// sequential fmaf chains (c ascending) and lower-index tie-break via packed
// (d_bits<<32|code) u64 atomicMin — same bits as the absmax-0 rounds 1-10.
// MFMA only prunes; margin covers the bf16 dot error bound (same as r9/r10).
//
// ws layout (4-byte units):
//   [0,1024)       hist (int)
//   [1024,2048)    ensq (float)
//   [2048,34816)   cb_bf16 (1024x64 ushort)
//   [34816,35840)  partials (float[1024])
//   [35840,68608)  idx (int[32768])

#define NROWS 32768
#define KC    1024
#define DD    64
#define HW    1024
#define CHW   65536
#define NCB   1024      // compute blocks (32 rows each)
#define NFB   1024      // fill blocks (32 enc rows each)
#define QMAX  1024

typedef float f32x2 __attribute__((ext_vector_type(2)));
typedef float f32x4 __attribute__((ext_vector_type(4)));
typedef short bf16x8 __attribute__((ext_vector_type(8)));

__device__ __forceinline__ unsigned short f2bf(float f) {
  unsigned x = __float_as_uint(f);
  return (unsigned short)((x + 0x7fffu + ((x >> 16) & 1u)) >> 16);  // RNE
}

__global__ __launch_bounds__(256) void vq_prep_kernel(
    const float* __restrict__ cb, float* __restrict__ ensq,
    unsigned short* __restrict__ cbb, int* __restrict__ hist) {
  int k = blockIdx.x * 256 + threadIdx.x;   // 4 x 256 = exactly KC
  hist[k] = 0;
  const float* row = cb + k * DD;
  float s = 0.f;
#pragma unroll
  for (int c = 0; c < DD; ++c) {
    float v = row[c];
    s = fmaf(v, v, s);                      // exact chain, c ascending
    cbb[k * DD + c] = f2bf(v);
  }
  ensq[k] = s;
}

__global__ __launch_bounds__(512) void vq_main_kernel(
    const float* __restrict__ z_e, const float* __restrict__ cb,
    const unsigned short* __restrict__ cbb, const float* __restrict__ ensq_g,
    float* __restrict__ qout, float* __restrict__ enc,
    int* __restrict__ idx_out, int* __restrict__ hist,
    float* __restrict__ partials) {
  const int tid = threadIdx.x;

  if (blockIdx.x >= NCB) {
    // ---------- fill path: zero 32 enc rows (128 KB), plain x4 stream ----------
    // enc base == 8 mod 16 B: each 4 KB row = head f32x2 + 255*f32x4 + tail f32x2.
    const int f = blockIdx.x - NCB;
    const int r = tid >> 4;          // 0..31
    const int m = tid & 15;          // 16-thread team per row
    float* rowp = enc + (size_t)(f * 32 + r) * KC;
    const f32x2 z2 = {0.f, 0.f};
    const f32x4 z4 = {0.f, 0.f, 0.f, 0.f};
    if (m == 0) *(f32x2*)rowp = z2;
    f32x4* chunks = (f32x4*)(rowp + 2);   // 16B-aligned, 255 chunks
#pragma unroll
    for (int j = 0; j < 15; ++j) chunks[m + 16 * j] = z4;
    if (m < 15) chunks[m + 240] = z4;
    else        *(f32x2*)(rowp + 1022) = z2;
    return;
  }

  // ---------- compute path: 32 rows, 8 waves = 2 row-tiles x 4 code-quarters ----------
  __shared__ float s_m[4][32];
  __shared__ float s_zsq[32];
  __shared__ unsigned long long s_key[32];
  __shared__ float s_loss[8];
  __shared__ int s_q[QMAX];
  __shared__ int s_cnt;

  const int lane = tid & 63;
  const int wave = __builtin_amdgcn_readfirstlane(tid >> 6);
  const int rt   = wave & 1;    // row tile: rows [16rt,16rt+16) of the block
  const int h    = wave >> 1;   // code quarter: [256h, 256h+256)
  const int cq   = lane >> 4;   // k-slice quarter 0..3
  const int cl   = lane & 15;   // col (code) / A-row index

  if (tid == 0) s_cnt = 0;
  if (wave == 0 && lane < 32) {
    const int n0 = blockIdx.x * 32 + lane;
    const float* zp0 = z_e + (size_t)(n0 >> 10) * CHW + (n0 & (HW - 1));
    float s = 0.f;
#pragma unroll
    for (int c = 0; c < DD; ++c) {
      float v = zp0[(size_t)c << 10];
      s = fmaf(v, v, s);               // exact chain — same bits as r1-r10
    }
    s_zsq[lane] = s;
    s_key[lane] = ~0ull;
  }

  // A-frags: this wave's 16 z-rows as bf16. Lane l: row = cl, k = cq*8+i.
  const int n  = blockIdx.x * 32 + rt * 16 + cl;
  const float* zp = z_e + (size_t)(n >> 10) * CHW + (n & (HW - 1));
  bf16x8 a0, a1;
#pragma unroll
  for (int i = 0; i < 8; ++i) {
    a0[i] = (short)f2bf(zp[(size_t)(cq * 8 + i) << 10]);
    a1[i] = (short)f2bf(zp[(size_t)(32 + cq * 8 + i) << 10]);
  }

  const int kbase = h * 256;
  const unsigned short* pb = cbb + (size_t)(kbase + cl) * DD + cq * 8;

  float bestm[4];
#pragma unroll
  for (int r = 0; r < 4; ++r) bestm[r] = 3.402823466e38f;

  // ---- pass 1: approx row-min over this wave's 256 codes (compact loop) ----
  {
    bf16x8 b0 = *(const bf16x8*)(pb);
    bf16x8 b1 = *(const bf16x8*)(pb + 32);
#pragma unroll 1
    for (int t = 0; t < 16; ++t) {
      const int tn = (t + 1) & 15;              // branch-free wrap prefetch
      bf16x8 nb0 = *(const bf16x8*)(pb + tn * 1024);
      bf16x8 nb1 = *(const bf16x8*)(pb + tn * 1024 + 32);
      f32x4 acc = {0.f, 0.f, 0.f, 0.f};
      acc = __builtin_amdgcn_mfma_f32_16x16x32_bf16(a0, b0, acc, 0, 0, 0);
      acc = __builtin_amdgcn_mfma_f32_16x16x32_bf16(a1, b1, acc, 0, 0, 0);
#pragma unroll
      for (int r = 0; r < 4; ++r) bestm[r] = fminf(bestm[r], -2.0f * acc[r]);
      b0 = nb0; b1 = nb1;
    }
  }
#pragma unroll
  for (int r = 0; r < 4; ++r) {
#pragma unroll
    for (int off = 1; off < 16; off <<= 1)
      bestm[r] = fminf(bestm[r], __shfl_xor(bestm[r], off, 64));
  }
  if (cl == 0) {
#pragma unroll
    for (int r = 0; r < 4; ++r) s_m[h][rt * 16 + cq * 4 + r] = bestm[r];
  }
  __syncthreads();

  float th[4];
#pragma unroll
  for (int r = 0; r < 4; ++r) {
    const int lr = rt * 16 + cq * 4 + r;
    float mh = fminf(fminf(s_m[0][lr], s_m[1][lr]), fminf(s_m[2][lr], s_m[3][lr]));
    th[r] = mh + 2.5e-4f * sqrtf(s_zsq[lr]) + 2.0e-4f;   // rigorous bf16 margin
  }

  // ---- pass 2: recompute, push candidates to LDS queue (3-instr body) ----
  {
    bf16x8 b0 = *(const bf16x8*)(pb);
    bf16x8 b1 = *(const bf16x8*)(pb + 32);
#pragma unroll 1
    for (int t = 0; t < 16; ++t) {
      const int tn = (t + 1) & 15;
      bf16x8 nb0 = *(const bf16x8*)(pb + tn * 1024);
      bf16x8 nb1 = *(const bf16x8*)(pb + tn * 1024 + 32);
      f32x4 acc = {0.f, 0.f, 0.f, 0.f};
      acc = __builtin_amdgcn_mfma_f32_16x16x32_bf16(a0, b0, acc, 0, 0, 0);
      acc = __builtin_amdgcn_mfma_f32_16x16x32_bf16(a1, b1, acc, 0, 0, 0);
      const int code = kbase + t * 16 + cl;
#pragma unroll
      for (int r = 0; r < 4; ++r) {
        if (-2.0f * acc[r] <= th[r]) {
          const int lr = rt * 16 + cq * 4 + r;
          int slot = atomicAdd(&s_cnt, 1);
          if (slot < QMAX) s_q[slot] = (code << 6) | lr;
        }
      }
      b0 = nb0; b1 = nb1;
    }
  }
  __syncthreads();

  // ---- candidate phase: one thread per entry, exact fp32 d + tie-break ----
  const int cnt = min(s_cnt, QMAX);
  for (int i = tid; i < cnt; i += 512) {
    const int e    = s_q[i];
    const int code = e >> 6;
    const int lr   = e & 63;
    const int n2   = blockIdx.x * 32 + lr;
    const float* zp2 = z_e + (size_t)(n2 >> 10) * CHW + (n2 & (HW - 1));
    const float* ce  = cb + (size_t)code * DD;
    float dot = 0.f;
#pragma unroll 8
    for (int c = 0; c < DD; ++c)
      dot = fmaf(zp2[(size_t)c << 10], ce[c], dot);        // exact chain
    float d = (s_zsq[lr] + ensq_g[code]) - 2.0f * dot;     // exact d-grid
    unsigned long long key =
        ((unsigned long long)__float_as_uint(d) << 32) | (unsigned)code;
    atomicMin(&s_key[lr], key);   // min d, then min index (numpy tie-break)
  }
  __syncthreads();

  // winners: hist + idx (scatter of 1.0s happens in finalize, after fill blocks)
  if (wave == 0 && lane < 32) {
    const int bi = (int)(unsigned)(s_key[lane] & 0xffffffffull);
    atomicAdd(&hist[bi], 1);
    idx_out[blockIdx.x * 32 + lane] = bi;
  }

  // fused epilogue: q_out + loss. Thread = (row = tid&31, chan group = tid>>5).
  const int row = tid & 31;
  const int cg  = tid >> 5;        // 16 groups x 4 channels
  const int bif = (int)(unsigned)(s_key[row] & 0xffffffffull);
  const int n3  = blockIdx.x * 32 + row;
  const float* zp3   = z_e + (size_t)(n3 >> 10) * CHW + (n3 & (HW - 1));
  const float* cbrow = cb + (size_t)bif * DD;
  float* qp = qout + (size_t)(n3 >> 10) * CHW + (n3 & (HW - 1));
  float lacc = 0.f;
#pragma unroll
  for (int j = 0; j < 4; ++j) {
    int c = cg * 4 + j;
    float v    = cbrow[c];
    float zc   = zp3[(size_t)c << 10];
    float diff = v - zc;               // matches ref (quantized - ze)
    qp[(size_t)c << 10] = zc + diff;   // matches ref ze + (quantized - ze)
    lacc = fmaf(diff, diff, lacc);
  }
#pragma unroll
  for (int off = 32; off > 0; off >>= 1) lacc += __shfl_down(lacc, off, 64);
  if (lane == 0) s_loss[wave] = lacc;
  __syncthreads();
  if (tid == 0) {
    float t = 0.f;
#pragma unroll
    for (int w2 = 0; w2 < 8; ++w2) t += s_loss[w2];
    partials[blockIdx.x] = t;
  }
}

__global__ __launch_bounds__(1024) void vq_finalize_kernel(
    const int* __restrict__ hist, const float* __restrict__ partials,
    const int* __restrict__ idx, float* __restrict__ enc,
    float* __restrict__ out_loss, float* __restrict__ out_ppl) {
  __shared__ float red[1024];
  const int t = threadIdx.x;

  // scatter the 1.0s (fill blocks finished in the previous dispatch)
  for (int i = t; i < NROWS; i += 1024)
    enc[(size_t)i * KC + idx[i]] = 1.0f;

  float p   = (float)hist[t] * (1.0f / 32768.0f);
  float ent = p * logf(p + 1e-10f);
  red[t] = ent;
  __syncthreads();
  for (int s = 512; s > 0; s >>= 1) {
    if (t < s) red[t] += red[t + s];
    __syncthreads();
  }
  float entropy = red[0];
  __syncthreads();

  red[t] = partials[t];
  __syncthreads();
  for (int s = 512; s > 0; s >>= 1) {
    if (t < s) red[t] += red[t + s];
    __syncthreads();
  }
  if (t == 0) {
    *out_loss = 0.25f * (red[0] * (1.0f / 2097152.0f));
    *out_ppl  = expf(-entropy);
  }
}

extern "C" void kernel_launch(void* const* d_in, const int* in_sizes, int n_in,
                              void* d_out, int out_size, void* d_ws, size_t ws_size,
                              hipStream_t stream) {
  const float* z_e = (const float*)d_in[0];
  const float* cb  = (const float*)d_in[1];

  float* out  = (float*)d_out;
  float* qout = out;                       // 2097152
  float* loss = out + 2097152;
  float* ppl  = out + 2097153;
  float* enc  = out + 2097154;             // 33554432 floats

  int*            hist     = (int*)d_ws;
  float*          ensq     = (float*)d_ws + 1024;
  unsigned short* cbb      = (unsigned short*)((float*)d_ws + 2048);
  float*          partials = (float*)d_ws + 34816;
  int*            idx      = (int*)d_ws + 35840;

  vq_prep_kernel<<<4, 256, 0, stream>>>(cb, ensq, cbb, hist);
  vq_main_kernel<<<NCB + NFB, 512, 0, stream>>>(z_e, cb, cbb, ensq, qout, enc,
                                                idx, hist, partials);
  vq_finalize_kernel<<<1, 1024, 0, stream>>>(hist, partials, idx, enc, loss, ppl);
}

// Round 12
// 117.525 us; speedup vs baseline: 1.4876x; 1.1155x over previous
//
#include <hip/hip_runtime.h>

// VQ-VAE vector quantizer, MI355X — MFMA filter (packed b-frags) + queued
// exact fp32 recheck, enc zero-fill overlapped as trailing blocks.
// z_e: [32,64,32,32] f32, codebook: [1024,64] f32.
// d_out = q_out(2097152) | loss(1) | perplexity(1) | encodings(33554432), f32.
//
// r11 lessons: (a) compute blocks exactly filled the machine -> fill ran
// serially after; now compute = 512 blocks (2/CU) and 8192 fill blocks
// co-schedule into the free wave slots. (b) b-frag loads were 64 scattered
// 16B chunks per instr; prep now PACKS the codebook in b-frag order so each
// load is one coalesced 1 KB burst. (c) VGPR=24 allocator strangle; 128-thr
// blocks + launch_bounds(128,2) give a 256-reg budget.
//
// Correctness: selection is ALWAYS exact fp32 d = (zsq + ensq) - 2*dot with
// sequential fmaf chains (c ascending) and lower-index tie-break via packed
// (d_bits<<32|code) u64 atomicMin — same bits as the absmax-0 rounds 1-11.
// MFMA only prunes; margin covers the bf16 dot error bound (3x validated).
//
// ws layout (4-byte units):
//   [0,1024)       hist (int)
//   [1024,2048)    ensq (float)
//   [2048,34816)   cb_packed (65536 ushort, b-frag order)
//   [34816,35840)  partials (float[1024], 512 used)
//   [35840,68608)  idx (int[32768])

#define NROWS 32768
#define KC    1024
#define DD    64
#define HW    1024
#define CHW   65536
#define NCB   512       // compute blocks, 64 rows each
#define NFB   8192      // fill blocks, 4 enc rows each
#define QMAX  1024

typedef float f32x2 __attribute__((ext_vector_type(2)));
typedef float f32x4 __attribute__((ext_vector_type(4)));
typedef short bf16x8 __attribute__((ext_vector_type(8)));

__device__ __forceinline__ unsigned short f2bf(float f) {
  unsigned x = __float_as_uint(f);
  return (unsigned short)((x + 0x7fffu + ((x >> 16) & 1u)) >> 16);  // RNE
}

__global__ __launch_bounds__(256) void vq_prep_kernel(
    const float* __restrict__ cb, float* __restrict__ ensq,
    unsigned short* __restrict__ cbp, int* __restrict__ hist) {
  int k = blockIdx.x * 256 + threadIdx.x;   // 4 x 256 = exactly KC
  hist[k] = 0;
  const float* row = cb + k * DD;
  const int t  = k >> 4;
  const int cl = k & 15;
  float s = 0.f;
#pragma unroll
  for (int c = 0; c < DD; ++c) {
    float v = row[c];
    s = fmaf(v, v, s);                      // exact chain, c ascending
    const int half = c >> 5, cq = (c & 31) >> 3, i = c & 7;
    // b-frag order: one wave tile-load = 64 lanes x 16B contiguous
    cbp[(((t * 2 + half) * 64) + cq * 16 + cl) * 8 + i] = f2bf(v);
  }
  ensq[k] = s;
}

__global__ __launch_bounds__(128, 2) void vq_main_kernel(
    const float* __restrict__ z_e, const float* __restrict__ cb,
    const unsigned short* __restrict__ cbp, const float* __restrict__ ensq_g,
    float* __restrict__ qout, float* __restrict__ enc,
    int* __restrict__ idx_out, int* __restrict__ hist,
    float* __restrict__ partials) {
  const int tid  = threadIdx.x;
  const int lane = tid & 63;
  const int wave = __builtin_amdgcn_readfirstlane(tid >> 6);  // 0/1

  if (blockIdx.x >= NCB) {
    // ---------- fill path: zero 4 enc rows (16 KB), plain coalesced f32x2 ----
    const int f = blockIdx.x - NCB;
#pragma unroll
    for (int rr = 0; rr < 2; ++rr) {
      const int row = f * 4 + wave * 2 + rr;
      f32x2* outp = (f32x2*)(enc + (size_t)row * KC);
      const f32x2 z2 = {0.f, 0.f};
#pragma unroll
      for (int j = 0; j < 8; ++j) outp[lane + 64 * j] = z2;
    }
    return;
  }

  // ---------- compute path: 64 rows, 2 waves x 32 rows x all 1024 codes ----
  __shared__ float s_zsq[64];
  __shared__ unsigned long long s_key[64];
  __shared__ float s_loss[2];
  __shared__ int s_q[QMAX];
  __shared__ int s_cnt;

  const int cq = lane >> 4;   // k-slice quarter 0..3 (D-row group)
  const int cl = lane & 15;   // code-within-tile / A-row index

  if (tid == 0) s_cnt = 0;
  if (tid < 64) {
    const int n0 = blockIdx.x * 64 + tid;
    const float* zp0 = z_e + (size_t)(n0 >> 10) * CHW + (n0 & (HW - 1));
    float s = 0.f;
#pragma unroll
    for (int c = 0; c < DD; ++c) {
      float v = zp0[(size_t)c << 10];
      s = fmaf(v, v, s);               // exact chain — same bits as r1-r11
    }
    s_zsq[tid] = s;
    s_key[tid] = ~0ull;
  }

  // A-frags: two 16-row tiles per wave. Lane l: A-row = cl, k = cq*8+i.
  const int rbase = blockIdx.x * 64 + wave * 32;
  const int n0 = rbase + cl, n1 = rbase + 16 + cl;
  const float* zpa = z_e + (size_t)(n0 >> 10) * CHW + (n0 & (HW - 1));
  const float* zpb = z_e + (size_t)(n1 >> 10) * CHW + (n1 & (HW - 1));
  bf16x8 a00, a01, a10, a11;
#pragma unroll
  for (int i = 0; i < 8; ++i) {
    a00[i] = (short)f2bf(zpa[(size_t)(cq * 8 + i) << 10]);
    a01[i] = (short)f2bf(zpa[(size_t)(32 + cq * 8 + i) << 10]);
    a10[i] = (short)f2bf(zpb[(size_t)(cq * 8 + i) << 10]);
    a11[i] = (short)f2bf(zpb[(size_t)(32 + cq * 8 + i) << 10]);
  }

  float bm0[4], bm1[4];
#pragma unroll
  for (int r = 0; r < 4; ++r) { bm0[r] = 3.402823466e38f; bm1[r] = 3.402823466e38f; }

  // ---- pass 1: approx row-min over all 1024 codes (coalesced packed feed) ----
  {
    bf16x8 b0 = *(const bf16x8*)(cbp + (size_t)lane * 8);
    bf16x8 b1 = *(const bf16x8*)(cbp + (size_t)(64 + lane) * 8);
#pragma unroll 1
    for (int t = 0; t < 64; ++t) {
      const int tn = (t + 1) & 63;
      bf16x8 nb0 = *(const bf16x8*)(cbp + (size_t)(tn * 128 + lane) * 8);
      bf16x8 nb1 = *(const bf16x8*)(cbp + (size_t)(tn * 128 + 64 + lane) * 8);
      f32x4 acc0 = {0.f, 0.f, 0.f, 0.f}, acc1 = {0.f, 0.f, 0.f, 0.f};
      acc0 = __builtin_amdgcn_mfma_f32_16x16x32_bf16(a00, b0, acc0, 0, 0, 0);
      acc0 = __builtin_amdgcn_mfma_f32_16x16x32_bf16(a01, b1, acc0, 0, 0, 0);
      acc1 = __builtin_amdgcn_mfma_f32_16x16x32_bf16(a10, b0, acc1, 0, 0, 0);
      acc1 = __builtin_amdgcn_mfma_f32_16x16x32_bf16(a11, b1, acc1, 0, 0, 0);
#pragma unroll
      for (int r = 0; r < 4; ++r) {
        bm0[r] = fminf(bm0[r], -2.0f * acc0[r]);
        bm1[r] = fminf(bm1[r], -2.0f * acc1[r]);
      }
      b0 = nb0; b1 = nb1;
    }
  }
  // col-reduce over the 16 code-lanes (lane bits 0..3)
#pragma unroll
  for (int r = 0; r < 4; ++r) {
#pragma unroll
    for (int off = 1; off < 16; off <<= 1) {
      bm0[r] = fminf(bm0[r], __shfl_xor(bm0[r], off, 64));
      bm1[r] = fminf(bm1[r], __shfl_xor(bm1[r], off, 64));
    }
  }
  __syncthreads();   // s_zsq, s_key, s_cnt visible

  // thresholds (uniform over cl): approx min + rigorous bf16 margin
  float th0[4], th1[4];
#pragma unroll
  for (int r = 0; r < 4; ++r) {
    th0[r] = bm0[r] + 2.5e-4f * sqrtf(s_zsq[wave * 32 + cq * 4 + r]) + 2.0e-4f;
    th1[r] = bm1[r] + 2.5e-4f * sqrtf(s_zsq[wave * 32 + 16 + cq * 4 + r]) + 2.0e-4f;
  }

  // ---- pass 2: recompute (deterministic), push candidates to LDS queue ----
  {
    bf16x8 b0 = *(const bf16x8*)(cbp + (size_t)lane * 8);
    bf16x8 b1 = *(const bf16x8*)(cbp + (size_t)(64 + lane) * 8);
#pragma unroll 1
    for (int t = 0; t < 64; ++t) {
      const int tn = (t + 1) & 63;
      bf16x8 nb0 = *(const bf16x8*)(cbp + (size_t)(tn * 128 + lane) * 8);
      bf16x8 nb1 = *(const bf16x8*)(cbp + (size_t)(tn * 128 + 64 + lane) * 8);
      f32x4 acc0 = {0.f, 0.f, 0.f, 0.f}, acc1 = {0.f, 0.f, 0.f, 0.f};
      acc0 = __builtin_amdgcn_mfma_f32_16x16x32_bf16(a00, b0, acc0, 0, 0, 0);
      acc0 = __builtin_amdgcn_mfma_f32_16x16x32_bf16(a01, b1, acc0, 0, 0, 0);
      acc1 = __builtin_amdgcn_mfma_f32_16x16x32_bf16(a10, b0, acc1, 0, 0, 0);
      acc1 = __builtin_amdgcn_mfma_f32_16x16x32_bf16(a11, b1, acc1, 0, 0, 0);
      const int code = t * 16 + cl;
#pragma unroll
      for (int r = 0; r < 4; ++r) {
        if (-2.0f * acc0[r] <= th0[r]) {
          int slot = atomicAdd(&s_cnt, 1);
          if (slot < QMAX) s_q[slot] = (code << 6) | (wave * 32 + cq * 4 + r);
        }
        if (-2.0f * acc1[r] <= th1[r]) {
          int slot = atomicAdd(&s_cnt, 1);
          if (slot < QMAX) s_q[slot] = (code << 6) | (wave * 32 + 16 + cq * 4 + r);
        }
      }
      b0 = nb0; b1 = nb1;
    }
  }
  __syncthreads();

  // ---- candidate phase: one thread per entry, exact fp32 d + tie-break ----
  const int cnt = min(s_cnt, QMAX);
#pragma unroll 1
  for (int i = tid; i < cnt; i += 128) {
    const int e    = s_q[i];
    const int code = e >> 6;
    const int lr   = e & 63;
    const int n2   = blockIdx.x * 64 + lr;
    const float* zp2 = z_e + (size_t)(n2 >> 10) * CHW + (n2 & (HW - 1));
    const float* ce  = cb + (size_t)code * DD;
    float dot = 0.f;
#pragma unroll 8
    for (int c = 0; c < DD; ++c)
      dot = fmaf(zp2[(size_t)c << 10], ce[c], dot);        // exact chain
    float d = (s_zsq[lr] + ensq_g[code]) - 2.0f * dot;     // exact d-grid
    unsigned long long key =
        ((unsigned long long)__float_as_uint(d) << 32) | (unsigned)code;
    atomicMin(&s_key[lr], key);   // min d, then min index (numpy tie-break)
  }
  __syncthreads();

  // winners: hist + idx (1.0-scatter happens in finalize, after fill blocks)
  if (tid < 64) {
    const int bi = (int)(unsigned)(s_key[tid] & 0xffffffffull);
    atomicAdd(&hist[bi], 1);
    idx_out[blockIdx.x * 64 + tid] = bi;
  }

  // fused epilogue: q_out + loss. Thread = (row = tid&63, half cg = tid>>6).
  const int row = tid & 63;
  const int cg  = tid >> 6;
  const int bif = (int)(unsigned)(s_key[row] & 0xffffffffull);
  const int n3  = blockIdx.x * 64 + row;
  const float* zp3   = z_e + (size_t)(n3 >> 10) * CHW + (n3 & (HW - 1));
  const float* cbrow = cb + (size_t)bif * DD;
  float* qp = qout + (size_t)(n3 >> 10) * CHW + (n3 & (HW - 1));
  float lacc = 0.f;
#pragma unroll
  for (int j = 0; j < 32; ++j) {
    int c = cg * 32 + j;
    float v    = cbrow[c];
    float zc   = zp3[(size_t)c << 10];
    float diff = v - zc;               // matches ref (quantized - ze)
    qp[(size_t)c << 10] = zc + diff;   // matches ref ze + (quantized - ze)
    lacc = fmaf(diff, diff, lacc);
  }
#pragma unroll
  for (int off = 32; off > 0; off >>= 1) lacc += __shfl_down(lacc, off, 64);
  if (lane == 0) s_loss[wave] = lacc;
  __syncthreads();
  if (tid == 0) partials[blockIdx.x] = s_loss[0] + s_loss[1];
}

__global__ __launch_bounds__(1024) void vq_finalize_kernel(
    const int* __restrict__ hist, const float* __restrict__ partials,
    const int* __restrict__ idx, float* __restrict__ enc,
    float* __restrict__ out_loss, float* __restrict__ out_ppl) {
  __shared__ float red[1024];
  const int t = threadIdx.x;

  // scatter the 1.0s (fill blocks finished in the previous dispatch)
#pragma unroll 1
  for (int i = t; i < NROWS; i += 1024)
    enc[(size_t)i * KC + idx[i]] = 1.0f;

  float p   = (float)hist[t] * (1.0f / 32768.0f);
  float ent = p * logf(p + 1e-10f);
  red[t] = ent;
  __syncthreads();
  for (int s = 512; s > 0; s >>= 1) {
    if (t < s) red[t] += red[t + s];
    __syncthreads();
  }
  float entropy = red[0];
  __syncthreads();

  red[t] = (t < NCB) ? partials[t] : 0.f;
  __syncthreads();
  for (int s = 512; s > 0; s >>= 1) {
    if (t < s) red[t] += red[t + s];
    __syncthreads();
  }
  if (t == 0) {
    *out_loss = 0.25f * (red[0] * (1.0f / 2097152.0f));
    *out_ppl  = expf(-entropy);
  }
}

extern "C" void kernel_launch(void* const* d_in, const int* in_sizes, int n_in,
                              void* d_out, int out_size, void* d_ws, size_t ws_size,
                              hipStream_t stream) {
  const float* z_e = (const float*)d_in[0];
  const float* cb  = (const float*)d_in[1];

  float* out  = (float*)d_out;
  float* qout = out;                       // 2097152
  float* loss = out + 2097152;
  float* ppl  = out + 2097153;
  float* enc  = out + 2097154;             // 33554432 floats

  int*            hist     = (int*)d_ws;
  float*          ensq     = (float*)d_ws + 1024;
  unsigned short* cbp      = (unsigned short*)((float*)d_ws + 2048);
  float*          partials = (float*)d_ws + 34816;
  int*            idx      = (int*)d_ws + 35840;

  vq_prep_kernel<<<4, 256, 0, stream>>>(cb, ensq, cbp, hist);
  vq_main_kernel<<<NCB + NFB, 128, 0, stream>>>(z_e, cb, cbp, ensq, qout, enc,
                                                idx, hist, partials);
  vq_finalize_kernel<<<1, 1024, 0, stream>>>(hist, partials, idx, enc, loss, ppl);
}

// Round 13
// 114.357 us; speedup vs baseline: 1.5288x; 1.0277x over previous
//
#include <hip/hip_runtime.h>

// VQ-VAE vector quantizer, MI355X — MFMA filter (packed b-frags) + queued
// exact fp32 recheck; enc zero-fill interleaved as co-resident blocks.
// z_e: [32,64,32,32] f32, codebook: [1024,64] f32.
// d_out = q_out(2097152) | loss(1) | perplexity(1) | encodings(33554432), f32.
//
// r12 lessons: (a) [compute...][fill...] ordering serialized the two phases ->
// roles now interleave via blockIdx%3 so every CU keeps both resident;
// (b) 1-deep prefetch left 4 waves/CU latency-bound at ~15% busy -> 16-row
// blocks (8/CU, 16 waves) + 2-deep prefetch ring; (c) plain fill stores
// thrashed L2 (codebook refetched ~60x) -> nontemporal fill stores in
// DEDICATED waves (r9's nt failure was same-wave fusion with compute loads).
//
// Correctness: selection is ALWAYS exact fp32 d = (zsq + ensq) - 2*dot with
// sequential fmaf chains (c ascending) and lower-index tie-break via packed
// (d_bits<<32|code) u64 atomicMin — same bits as the absmax-0 rounds 1-12.
// MFMA only prunes; margin covers the bf16 dot error bound (4x validated).
//
// ws layout (4-byte units):
//   [0,1024)       hist (int)
//   [1024,2048)    ensq (float)
//   [2048,34816)   cb_packed (65536 ushort, b-frag order)
//   [34816,36864)  partials (float[2048])
//   [36864,69632)  idx (int[32768])

#define NROWS 32768
#define KC    1024
#define DD    64
#define HW    1024
#define CHW   65536
#define NCB   2048      // compute blocks, 16 rows each
#define NFB   4096      // fill blocks, 8 enc rows each
#define QMAX  256

typedef float f32x2 __attribute__((ext_vector_type(2)));
typedef float f32x4 __attribute__((ext_vector_type(4)));
typedef short bf16x8 __attribute__((ext_vector_type(8)));

__device__ __forceinline__ unsigned short f2bf(float f) {
  unsigned x = __float_as_uint(f);
  return (unsigned short)((x + 0x7fffu + ((x >> 16) & 1u)) >> 16);  // RNE
}

__global__ __launch_bounds__(256) void vq_prep_kernel(
    const float* __restrict__ cb, float* __restrict__ ensq,
    unsigned short* __restrict__ cbp, int* __restrict__ hist) {
  int k = blockIdx.x * 256 + threadIdx.x;   // 4 x 256 = exactly KC
  hist[k] = 0;
  const float* row = cb + k * DD;
  const int t  = k >> 4;
  const int cl = k & 15;
  float s = 0.f;
#pragma unroll
  for (int c = 0; c < DD; ++c) {
    float v = row[c];
    s = fmaf(v, v, s);                      // exact chain, c ascending
    const int half = c >> 5, cq = (c & 31) >> 3, i = c & 7;
    // b-frag order: one wave tile-load = 64 lanes x 16B contiguous
    cbp[(((t * 2 + half) * 64) + cq * 16 + cl) * 8 + i] = f2bf(v);
  }
  ensq[k] = s;
}

__global__ __launch_bounds__(128, 4) void vq_main_kernel(
    const float* __restrict__ z_e, const float* __restrict__ cb,
    const unsigned short* __restrict__ cbp, const float* __restrict__ ensq_g,
    float* __restrict__ qout, float* __restrict__ enc,
    int* __restrict__ idx_out, int* __restrict__ hist,
    float* __restrict__ partials) {
  const int tid  = threadIdx.x;
  const int bid  = blockIdx.x;

  if (bid % 3 != 0) {
    // ---------- fill path (4096 blocks): zero 8 enc rows (32 KB), NT stores ----
    // enc base == 8 mod 16 B: each 4 KB row = head f32x2 + 255*f32x4 + tail f32x2.
    const int f = 2 * (bid / 3) + (bid % 3) - 1;   // 0..4095
    const int r = tid >> 4;          // 0..7
    const int m = tid & 15;          // 16-thread team per row
    float* rowp = enc + (size_t)(f * 8 + r) * KC;
    const f32x2 z2 = {0.f, 0.f};
    const f32x4 z4 = {0.f, 0.f, 0.f, 0.f};
    if (m == 0) __builtin_nontemporal_store(z2, (f32x2*)rowp);
    f32x4* chunks = (f32x4*)(rowp + 2);   // 16B-aligned, 255 chunks
#pragma unroll
    for (int j = 0; j < 15; ++j)
      __builtin_nontemporal_store(z4, &chunks[m + 16 * j]);
    if (m < 15) __builtin_nontemporal_store(z4, &chunks[m + 240]);
    else        __builtin_nontemporal_store(z2, (f32x2*)(rowp + 1022));
    return;
  }

  // ---------- compute path (2048 blocks): 16 rows x 1024 codes ----------
  __shared__ float s_zsq[16];
  __shared__ float s_m[2][16];
  __shared__ unsigned long long s_key[16];
  __shared__ float s_loss[2];
  __shared__ int s_q[QMAX];
  __shared__ int s_cnt;

  const int cblk = bid / 3;            // 0..2047
  const int rb   = cblk * 16;          // first row
  const int lane = tid & 63;
  const int w    = __builtin_amdgcn_readfirstlane(tid >> 6);  // code half 0/1
  const int cq   = lane >> 4;          // k-slice quarter / acc row group
  const int cl   = lane & 15;          // code-in-tile / A-row

  if (tid == 0) s_cnt = 0;
  if (tid < 16) {
    const int n0 = rb + tid;
    const float* zp0 = z_e + (size_t)(n0 >> 10) * CHW + (n0 & (HW - 1));
    float s = 0.f;
#pragma unroll
    for (int c = 0; c < DD; ++c) {
      float v = zp0[(size_t)c << 10];
      s = fmaf(v, v, s);               // exact chain — same bits as r1-r12
    }
    s_zsq[tid] = s;
    s_key[tid] = ~0ull;
  }

  // A-frags: rows rb..rb+16. Lane l: A-row = cl, k = cq*8+i.
  const int n = rb + cl;
  const float* zp = z_e + (size_t)(n >> 10) * CHW + (n & (HW - 1));
  bf16x8 a0, a1;
#pragma unroll
  for (int i = 0; i < 8; ++i) {
    a0[i] = (short)f2bf(zp[(size_t)(cq * 8 + i) << 10]);
    a1[i] = (short)f2bf(zp[(size_t)(32 + cq * 8 + i) << 10]);
  }

  // this wave's 32 code tiles: global tile T = w*32 + t, frag pair at
  // cbp + (T*128 + lane)*8 and +512 shorts.
  const unsigned short* base = cbp + ((size_t)(w * 32) * 128 + lane) * 8;

  float bm[4];
#pragma unroll
  for (int r = 0; r < 4; ++r) bm[r] = 3.402823466e38f;

  // ---- pass 1: approx row-min, 2-deep prefetch ring ----
  {
    bf16x8 c0 = *(const bf16x8*)(base);
    bf16x8 c1 = *(const bf16x8*)(base + 512);
    bf16x8 d0 = *(const bf16x8*)(base + 1024);
    bf16x8 d1 = *(const bf16x8*)(base + 1536);
#pragma unroll 1
    for (int t = 0; t < 32; t += 2) {
      const int t2 = (t + 2) & 31, t3 = (t + 3) & 31;
      bf16x8 e0 = *(const bf16x8*)(base + t2 * 1024);
      bf16x8 e1 = *(const bf16x8*)(base + t2 * 1024 + 512);
      bf16x8 f0 = *(const bf16x8*)(base + t3 * 1024);
      bf16x8 f1 = *(const bf16x8*)(base + t3 * 1024 + 512);
      f32x4 acc = {0.f, 0.f, 0.f, 0.f};
      acc = __builtin_amdgcn_mfma_f32_16x16x32_bf16(a0, c0, acc, 0, 0, 0);
      acc = __builtin_amdgcn_mfma_f32_16x16x32_bf16(a1, c1, acc, 0, 0, 0);
      f32x4 acd = {0.f, 0.f, 0.f, 0.f};
      acd = __builtin_amdgcn_mfma_f32_16x16x32_bf16(a0, d0, acd, 0, 0, 0);
      acd = __builtin_amdgcn_mfma_f32_16x16x32_bf16(a1, d1, acd, 0, 0, 0);
#pragma unroll
      for (int r = 0; r < 4; ++r)
        bm[r] = fminf(bm[r], fminf(-2.0f * acc[r], -2.0f * acd[r]));
      c0 = e0; c1 = e1; d0 = f0; d1 = f1;
    }
  }
  // col-reduce over the 16 code-lanes (lane bits 0..3)
#pragma unroll
  for (int r = 0; r < 4; ++r) {
#pragma unroll
    for (int off = 1; off < 16; off <<= 1)
      bm[r] = fminf(bm[r], __shfl_xor(bm[r], off, 64));
  }
  if (cl == 0) {
#pragma unroll
    for (int r = 0; r < 4; ++r) s_m[w][cq * 4 + r] = bm[r];
  }
  __syncthreads();

  // thresholds: global approx min + rigorous bf16 margin
  float th[4];
#pragma unroll
  for (int r = 0; r < 4; ++r) {
    const int row = cq * 4 + r;
    float mh = fminf(s_m[0][row], s_m[1][row]);
    th[r] = mh + 2.5e-4f * sqrtf(s_zsq[row]) + 2.0e-4f;
  }

  // ---- pass 2: recompute (deterministic), push candidates ----
  {
    bf16x8 c0 = *(const bf16x8*)(base);
    bf16x8 c1 = *(const bf16x8*)(base + 512);
    bf16x8 d0 = *(const bf16x8*)(base + 1024);
    bf16x8 d1 = *(const bf16x8*)(base + 1536);
#pragma unroll 1
    for (int t = 0; t < 32; t += 2) {
      const int t2 = (t + 2) & 31, t3 = (t + 3) & 31;
      bf16x8 e0 = *(const bf16x8*)(base + t2 * 1024);
      bf16x8 e1 = *(const bf16x8*)(base + t2 * 1024 + 512);
      bf16x8 f0 = *(const bf16x8*)(base + t3 * 1024);
      bf16x8 f1 = *(const bf16x8*)(base + t3 * 1024 + 512);
      f32x4 acc = {0.f, 0.f, 0.f, 0.f};
      acc = __builtin_amdgcn_mfma_f32_16x16x32_bf16(a0, c0, acc, 0, 0, 0);
      acc = __builtin_amdgcn_mfma_f32_16x16x32_bf16(a1, c1, acc, 0, 0, 0);
      f32x4 acd = {0.f, 0.f, 0.f, 0.f};
      acd = __builtin_amdgcn_mfma_f32_16x16x32_bf16(a0, d0, acd, 0, 0, 0);
      acd = __builtin_amdgcn_mfma_f32_16x16x32_bf16(a1, d1, acd, 0, 0, 0);
      const int code0 = w * 512 + t * 16 + cl;
#pragma unroll
      for (int r = 0; r < 4; ++r) {
        if (-2.0f * acc[r] <= th[r]) {
          int slot = atomicAdd(&s_cnt, 1);
          if (slot < QMAX) s_q[slot] = (code0 << 4) | (cq * 4 + r);
        }
        if (-2.0f * acd[r] <= th[r]) {
          int slot = atomicAdd(&s_cnt, 1);
          if (slot < QMAX) s_q[slot] = ((code0 + 16) << 4) | (cq * 4 + r);
        }
      }
      c0 = e0; c1 = e1; d0 = f0; d1 = f1;
    }
  }
  __syncthreads();

  // ---- candidate phase: one thread per entry, exact fp32 d + tie-break ----
  const int cnt = min(s_cnt, QMAX);
#pragma unroll 1
  for (int i = tid; i < cnt; i += 128) {
    const int e    = s_q[i];
    const int code = e >> 4;
    const int lr   = e & 15;
    const int n2   = rb + lr;
    const float* zp2 = z_e + (size_t)(n2 >> 10) * CHW + (n2 & (HW - 1));
    const float* ce  = cb + (size_t)code * DD;
    float dot = 0.f;
#pragma unroll 8
    for (int c = 0; c < DD; ++c)
      dot = fmaf(zp2[(size_t)c << 10], ce[c], dot);        // exact chain
    float d = (s_zsq[lr] + ensq_g[code]) - 2.0f * dot;     // exact d-grid
    unsigned long long key =
        ((unsigned long long)__float_as_uint(d) << 32) | (unsigned)code;
    atomicMin(&s_key[lr], key);   // min d, then min index (numpy tie-break)
  }
  __syncthreads();

  // winners: hist + idx (1.0-scatter happens in finalize)
  if (tid < 16) {
    const int bi = (int)(unsigned)(s_key[tid] & 0xffffffffull);
    atomicAdd(&hist[bi], 1);
    idx_out[rb + tid] = bi;
  }

  // fused epilogue: q_out + loss. Thread = (row = tid&15, cg = tid>>4).
  const int row = tid & 15;
  const int cg  = tid >> 4;        // 8 groups x 8 channels
  const int bif = (int)(unsigned)(s_key[row] & 0xffffffffull);
  const int n3  = rb + row;
  const float* zp3   = z_e + (size_t)(n3 >> 10) * CHW + (n3 & (HW - 1));
  const float* cbrow = cb + (size_t)bif * DD;
  float* qp = qout + (size_t)(n3 >> 10) * CHW + (n3 & (HW - 1));
  float lacc = 0.f;
#pragma unroll
  for (int j = 0; j < 8; ++j) {
    int c = cg * 8 + j;
    float v    = cbrow[c];
    float zc   = zp3[(size_t)c << 10];
    float diff = v - zc;               // matches ref (quantized - ze)
    qp[(size_t)c << 10] = zc + diff;   // matches ref ze + (quantized - ze)
    lacc = fmaf(diff, diff, lacc);
  }
#pragma unroll
  for (int off = 32; off > 0; off >>= 1) lacc += __shfl_down(lacc, off, 64);
  if (lane == 0) s_loss[w] = lacc;
  __syncthreads();
  if (tid == 0) partials[cblk] = s_loss[0] + s_loss[1];
}

__global__ __launch_bounds__(1024) void vq_finalize_kernel(
    const int* __restrict__ hist, const float* __restrict__ partials,
    const int* __restrict__ idx, float* __restrict__ enc,
    float* __restrict__ out_loss, float* __restrict__ out_ppl) {
  __shared__ float red[1024];
  const int t = threadIdx.x;

  // scatter the 1.0s (fill blocks finished in the previous dispatch)
#pragma unroll 1
  for (int i = t; i < NROWS; i += 1024)
    enc[(size_t)i * KC + idx[i]] = 1.0f;

  float p   = (float)hist[t] * (1.0f / 32768.0f);
  float ent = p * logf(p + 1e-10f);
  red[t] = ent;
  __syncthreads();
  for (int s = 512; s > 0; s >>= 1) {
    if (t < s) red[t] += red[t + s];
    __syncthreads();
  }
  float entropy = red[0];
  __syncthreads();

  red[t] = partials[t] + partials[t + 1024];
  __syncthreads();
  for (int s = 512; s > 0; s >>= 1) {
    if (t < s) red[t] += red[t + s];
    __syncthreads();
  }
  if (t == 0) {
    *out_loss = 0.25f * (red[0] * (1.0f / 2097152.0f));
    *out_ppl  = expf(-entropy);
  }
}

extern "C" void kernel_launch(void* const* d_in, const int* in_sizes, int n_in,
                              void* d_out, int out_size, void* d_ws, size_t ws_size,
                              hipStream_t stream) {
  const float* z_e = (const float*)d_in[0];
  const float* cb  = (const float*)d_in[1];

  float* out  = (float*)d_out;
  float* qout = out;                       // 2097152
  float* loss = out + 2097152;
  float* ppl  = out + 2097153;
  float* enc  = out + 2097154;             // 33554432 floats

  int*            hist     = (int*)d_ws;
  float*          ensq     = (float*)d_ws + 1024;
  unsigned short* cbp      = (unsigned short*)((float*)d_ws + 2048);
  float*          partials = (float*)d_ws + 34816;
  int*            idx      = (int*)d_ws + 36864;

  vq_prep_kernel<<<4, 256, 0, stream>>>(cb, ensq, cbp, hist);
  vq_main_kernel<<<NCB + NFB, 128, 0, stream>>>(z_e, cb, cbp, ensq, qout, enc,
                                                idx, hist, partials);
  vq_finalize_kernel<<<1, 1024, 0, stream>>>(hist, partials, idx, enc, loss, ppl);
}